// Round 13
// baseline (1320.884 us; speedup 1.0000x reference)
//
#include <hip/hip_runtime.h>
#include <math.h>

#define BTOT  65536
#define NN    6
#define NEG   0.2f
#define MASKV (-1e9f)

typedef short bf16x8 __attribute__((ext_vector_type(8)));
typedef float f32x4  __attribute__((ext_vector_type(4)));

// ws layout: fragment-linear hi/lo bf16 weights, 1024B per frag, [nt][kk][hi/lo]
#define OFF_W0 0u
#define OFF_W1 131072u
#define OFF_W2 393216u
#define OFF_P1 655360u
#define OFF_P2 3801088u
#define WS_NEED 4063232ull
// appended aS/aD fragments (W@a_src | W@a_dst as B-columns 0,1)
#define OFF_AS0 4063232u
#define OFF_AS1 4071424u
#define OFF_AS2 4087808u
#define WS_NEED_AS 4104192ull

__device__ __forceinline__ f32x4 mfma16(bf16x8 a, bf16x8 b, f32x4 c){
  return __builtin_amdgcn_mfma_f32_16x16x32_bf16(a, b, c, 0, 0, 0);
}

// LDS-only barrier: drain DS ops, hw barrier; vmem register loads stay in flight.
#define BAR() do { \
  asm volatile("s_waitcnt lgkmcnt(0)" ::: "memory"); \
  __builtin_amdgcn_s_barrier(); \
  asm volatile("" ::: "memory"); \
} while (0)

// LDS map: A0 frags [0,48K), A1 [48K,96K), Wh fp32 [96K,145.5K), psd [145.5K,+768B)
#define WH_BASE 24576   // word offset of shared Wh buffer

__device__ __forceinline__ int hwordL(int r, int c){
  return WH_BASE + r*264 + (c ^ ((r&7)<<2));
}
__device__ __forceinline__ int ACH(int frag, int p, int kk){
  return (frag*64 + (p ^ (kk&7) ^ ((p>>4)&3)))*8;
}

// truncation split: x = hi + lo (exact residual)
__device__ __forceinline__ void split4(float4 x, ushort4& h, ushort4& l){
  float xs[4] = {x.x, x.y, x.z, x.w};
  unsigned hu[4], lu[4];
  #pragma unroll
  for (int e=0;e<4;++e){
    unsigned u = __float_as_uint(xs[e]);
    float hf = __uint_as_float(u & 0xFFFF0000u);
    hu[e] = u >> 16;
    lu[e] = __float_as_uint(xs[e] - hf) >> 16;
  }
  h = make_ushort4((unsigned short)hu[0],(unsigned short)hu[1],
                   (unsigned short)hu[2],(unsigned short)hu[3]);
  l = make_ushort4((unsigned short)lu[0],(unsigned short)lu[1],
                   (unsigned short)lu[2],(unsigned short)lu[3]);
}

// ---------------- pre-kernel: fp32 weights -> frag-linear hi/lo bf16 in ws -------------
__global__ __launch_bounds__(64) void fragize(
    const float* __restrict__ W0, const float* __restrict__ W1,
    const float* __restrict__ W2, const float* __restrict__ P1w,
    const float* __restrict__ P2w,
    const float* __restrict__ a0v, const float* __restrict__ a1v,
    const float* __restrict__ a2v, char* __restrict__ ws)
{
  int fid = blockIdx.x;
  int lane = threadIdx.x;
  if (fid >= 1984){
    int idx = fid - 1984;
    const float* W; const float* av; unsigned off; int kk;
    if (idx < 4)       { W = W0; av = a0v; off = OFF_AS0; kk = idx; }
    else if (idx < 12) { W = W1; av = a1v; off = OFF_AS1; kk = idx - 4; }
    else               { W = W2; av = a2v; off = OFF_AS2; kk = idx - 12; }
    int col = lane & 15;
    int kb  = kk*32 + (lane >> 4)*8;
    bf16x8 h, l;
    #pragma unroll
    for (int e=0;e<8;++e){
      float x = 0.f;
      if (col < 2){
        const float* ap = av + col*256;
        const float* wrow = W + (size_t)(kb+e)*256;
        float acc = 0.f;
        for (int o=0;o<256;o+=4){
          float4 wv = *(const float4*)(wrow + o);
          float4 a4 = *(const float4*)(ap + o);
          acc += wv.x*a4.x + wv.y*a4.y + wv.z*a4.z + wv.w*a4.w;
        }
        x = acc;
      }
      unsigned u = __float_as_uint(x);
      float hf = __uint_as_float(u & 0xFFFF0000u);
      h[e] = (short)(u >> 16);
      l[e] = (short)(__float_as_uint(x - hf) >> 16);
    }
    char* dst = ws + off + (size_t)kk*2048 + (size_t)lane*16;
    *(bf16x8*)dst = h;
    *(bf16x8*)(dst + 1024) = l;
    return;
  }
  const float* src; int KK, N; unsigned off; int idx;
  if (fid < 64)        { src = W0;  KK = 4;  N = 256; off = OFF_W0; idx = fid; }
  else if (fid < 192)  { src = W1;  KK = 8;  N = 256; off = OFF_W1; idx = fid - 64; }
  else if (fid < 320)  { src = W2;  KK = 8;  N = 256; off = OFF_W2; idx = fid - 192; }
  else if (fid < 1856) { src = P1w; KK = 48; N = 512; off = OFF_P1; idx = fid - 320; }
  else                 { src = P2w; KK = 16; N = 128; off = OFF_P2; idx = fid - 1856; }
  int nt = idx / KK, kk = idx % KK;
  int n  = nt*16 + (lane & 15);
  int kb = kk*32 + (lane >> 4)*8;
  bf16x8 h, l;
  #pragma unroll
  for (int e=0;e<8;++e){
    float x = src[(size_t)(kb+e)*N + n];
    unsigned u = __float_as_uint(x);
    float hf = __uint_as_float(u & 0xFFFF0000u);
    h[e] = (short)(u >> 16);
    l[e] = (short)(__float_as_uint(x - hf) >> 16);
  }
  char* dst = ws + off + (size_t)idx*2048 + (size_t)lane*16;
  *(bf16x8*)dst = h;
  *(bf16x8*)(dst + 1024) = l;
}

#define GLOADSET(S, kv) do{ \
    (S)[0] = *(const bf16x8*)(wb0 + (kv)*2048); \
    (S)[1] = *(const bf16x8*)(wb0 + (kv)*2048 + 1024); \
    (S)[2] = *(const bf16x8*)(wb1 + (kv)*2048); \
    (S)[3] = *(const bf16x8*)(wb1 + (kv)*2048 + 1024); } while(0)

// precompute swizzled LDS base pointers, one per (kk&7)
#define MAKE_AP(ap, ab, baseu) \
  const unsigned short* ap[8]; \
  _Pragma("unroll") \
  for (int t=0;t<8;++t) \
    ap[t] = (ab) + (baseu) + (size_t)((lane ^ t ^ ((lane>>4)&3)))*8;

// ---------------- group GEMM (2 barriers: kk==1 + end) ---------------------------------
template<int KK, bool AS>
__device__ __forceinline__ void do_gemm(const unsigned short* ab,
    const char* __restrict__ wf, const char* __restrict__ wfS,
    int g, int wl, int lane, f32x4 (&acc)[3][2], float* psd)
{
  #pragma unroll
  for (int mt=0;mt<3;++mt){
    acc[mt][0] = f32x4{0.f,0.f,0.f,0.f};
    acc[mt][1] = f32x4{0.f,0.f,0.f,0.f};
  }
  MAKE_AP(ap, ab, (size_t)g*24576);
  const char* wb0 = wf + (size_t)(2*wl)*KK*2048 + (size_t)lane*16;
  const char* wb1 = wb0 + (size_t)KK*2048;
  bf16x8 B[4][4];
  GLOADSET(B[0], 0);
  GLOADSET(B[1], 1);
  GLOADSET(B[2], 2);
  const bool doX = AS && (wl >= 5);
  const int mtx = wl - 5;
  const char* wbS = wfS + (size_t)lane*16;
  bf16x8 S[4][2];
  f32x4 accX = {0.f,0.f,0.f,0.f};
  if (doX){
    #pragma unroll
    for (int t=0;t<3;++t){
      S[t][0] = *(const bf16x8*)(wbS + t*2048);
      S[t][1] = *(const bf16x8*)(wbS + t*2048 + 1024);
    }
  }
  #pragma unroll
  for (int kk=0; kk<KK; ++kk){
    if (kk+3 < KK){
      GLOADSET(B[(kk+3)&3], kk+3);
      if (doX){
        S[(kk+3)&3][0] = *(const bf16x8*)(wbS + (kk+3)*2048);
        S[(kk+3)&3][1] = *(const bf16x8*)(wbS + (kk+3)*2048 + 1024);
      }
    }
    if (kk == 1) BAR();   // 1:KK-1 split: bulk of GEMM overlaps the attn tail
    const unsigned short* a0p = ap[kk&7];
    __builtin_amdgcn_s_setprio(1);
    #pragma unroll
    for (int mt=0; mt<3; ++mt){
      bf16x8 ah = *(const bf16x8*)(a0p + (mt*KK + kk)*512);
      bf16x8 al = *(const bf16x8*)(a0p + ((3+mt)*KK + kk)*512);
      acc[mt][0] = mfma16(ah, B[kk&3][0], acc[mt][0]);
      acc[mt][1] = mfma16(ah, B[kk&3][2], acc[mt][1]);
      acc[mt][0] = mfma16(al, B[kk&3][0], acc[mt][0]);
      acc[mt][1] = mfma16(al, B[kk&3][2], acc[mt][1]);
      acc[mt][0] = mfma16(ah, B[kk&3][1], acc[mt][0]);
      acc[mt][1] = mfma16(ah, B[kk&3][3], acc[mt][1]);
      if (doX && mt == mtx){
        accX = mfma16(ah, S[kk&3][0], accX);
        accX = mfma16(al, S[kk&3][0], accX);
        accX = mfma16(ah, S[kk&3][1], accX);
      }
    }
    __builtin_amdgcn_s_setprio(0);
  }
  if (doX && (lane & 15) < 2){
    int colx  = lane & 15;
    int rbase = mtx*16 + (lane >> 4)*4;
    #pragma unroll
    for (int v=0;v<4;++v)
      psd[g*96 + (rbase+v)*2 + colx] = accX[v];
  }
  BAR();
}

// gr-write from held attn output
__device__ __forceinline__ void write_gr(unsigned short* ab, const float (*nh)[4],
    const float* rsum, int item_blk, int lane)
{
  const int kkl  = lane >> 3;
  const int kg2  = (lane >> 1) & 3;
  const int elem = (lane & 1) * 4;
  #pragma unroll
  for (int i=0;i<NN;++i){
    float rinv = 1.0f / rsum[i];
    float4 v;
    v.x = fmaxf(nh[i][0]*rinv, 0.f);
    v.y = fmaxf(nh[i][1]*rinv, 0.f);
    v.z = fmaxf(nh[i][2]*rinv, 0.f);
    v.w = fmaxf(nh[i][3]*rinv, 0.f);
    ushort4 hv, lv; split4(v, hv, lv);
    int kkg = i*8 + kkl;
    int p   = kg2*16 + item_blk;
    *(ushort4*)(ab + ACH(kkg,      p, kkg) + elem) = hv;
    *(ushort4*)(ab + ACH(48 + kkg, p, kkg) + elem) = lv;
  }
}

// ---------------- Wh-write + attention (2 barriers); R10 scalar math -------------------
// MODE 0: write h' to own A-frags. MODE 1: hold. MODE 2: write gr.
template<int MODE, bool AS>
__device__ __forceinline__ void do_whattn(float* hb, unsigned short* ab,
    const f32x4 (&acc)[3][2], const float* __restrict__ avec,
    int g, int wl, int lane, unsigned long long mz,
    float (*nhold)[4], float* rshold, const float* psd)
{
  const int arow = lane & 15, kgrp = lane >> 4;
  #pragma unroll
  for (int mt=0;mt<3;++mt)
    #pragma unroll
    for (int nt=0;nt<2;++nt)
      #pragma unroll
      for (int v=0;v<4;++v)
        hb[hwordL(mt*16 + kgrp*4 + v, (wl*2+nt)*16 + arow)] = acc[mt][nt][v];
  BAR();

  const int c0 = lane << 2;
  float wh[NN][4];
  #pragma unroll
  for (int i=0;i<NN;++i){
    float4 t = *(const float4*)(hb + hwordL(wl*NN+i, c0));
    wh[i][0]=t.x; wh[i][1]=t.y; wh[i][2]=t.z; wh[i][3]=t.w;
  }
  float ps[NN], pd[NN];
  if (AS){
    #pragma unroll
    for (int i=0;i<NN;++i){
      float2 t = *(const float2*)(psd + g*96 + (wl*NN+i)*2);
      ps[i] = t.x; pd[i] = t.y;
    }
  } else {
    float4 as4 = *(const float4*)(avec + c0);
    float4 ad4 = *(const float4*)(avec + 256 + c0);
    #pragma unroll
    for (int i=0;i<NN;++i){
      ps[i] = wh[i][0]*as4.x + wh[i][1]*as4.y + wh[i][2]*as4.z + wh[i][3]*as4.w;
      pd[i] = wh[i][0]*ad4.x + wh[i][1]*ad4.y + wh[i][2]*ad4.z + wh[i][3]*ad4.w;
    }
    for (int off=32; off>0; off>>=1){
      #pragma unroll
      for (int i=0;i<NN;++i){ ps[i]+=__shfl_xor(ps[i],off); pd[i]+=__shfl_xor(pd[i],off); }
    }
  }
  // rmax via monotonicity of leaky: max_j leaky(ps+pd_j) = leaky(ps + max_j pd_j)
  float rmax[NN];
  #pragma unroll
  for (int i=0;i<NN;++i){
    float mp = -3.4e38f;
    #pragma unroll
    for (int j=0;j<NN;++j){
      float pj = ((mz >> (i*6+j)) & 1ull) ? -3.4e38f : pd[j];
      mp = fmaxf(mp, pj);
    }
    float t  = ps[i] + mp;
    float lk = fmaxf(t, NEG*t);
    rmax[i] = fmaxf(lk, MASKV);
  }
  float rsum[NN] = {0.f,0.f,0.f,0.f,0.f,0.f};
  float nh[NN][4];
  #pragma unroll
  for (int i=0;i<NN;++i){ nh[i][0]=0.f; nh[i][1]=0.f; nh[i][2]=0.f; nh[i][3]=0.f; }
  #pragma unroll
  for (int j=0;j<NN;++j){
    float s[NN];
    #pragma unroll
    for (int i=0;i<NN;++i){
      float t = ps[i] + pd[j];
      float e = fmaxf(t, NEG*t);
      e = ((mz >> (i*6+j)) & 1ull) ? MASKV : e;
      s[i] = __expf(e - rmax[i]);
      rsum[i] += s[i];
    }
    #pragma unroll
    for (int i=0;i<NN;++i){
      nh[i][0] = fmaf(s[i], wh[j][0], nh[i][0]);
      nh[i][1] = fmaf(s[i], wh[j][1], nh[i][1]);
      nh[i][2] = fmaf(s[i], wh[j][2], nh[i][2]);
      nh[i][3] = fmaf(s[i], wh[j][3], nh[i][3]);
    }
  }

  if (MODE == 0){
    const int kkl  = lane >> 3;
    const int kg2  = (lane >> 1) & 3;
    const int elem = (lane & 1) * 4;
    #pragma unroll
    for (int i=0;i<NN;++i){
      float rinv = 1.0f / rsum[i];
      float4 v;
      v.x = fmaxf(nh[i][0]*rinv, 0.f);
      v.y = fmaxf(nh[i][1]*rinv, 0.f);
      v.z = fmaxf(nh[i][2]*rinv, 0.f);
      v.w = fmaxf(nh[i][3]*rinv, 0.f);
      ushort4 hv, lv; split4(v, hv, lv);
      int rl = wl*NN + i;
      int mt = rl >> 4;
      int p  = kg2*16 + (rl & 15);
      *(ushort4*)(ab + ACH(g*48 + mt*8 + kkl,      p, kkl) + elem) = hv;
      *(ushort4*)(ab + ACH(g*48 + 24 + mt*8 + kkl, p, kkl) + elem) = lv;
    }
  } else if (MODE == 1){
    #pragma unroll
    for (int i=0;i<NN;++i){
      nhold[i][0]=nh[i][0]; nhold[i][1]=nh[i][1];
      nhold[i][2]=nh[i][2]; nhold[i][3]=nh[i][3];
      rshold[i]=rsum[i];
    }
  } else {
    write_gr(ab, nh, rsum, g*8 + wl, lane);
  }
  BAR();
}

__device__ __forceinline__ void idle_step(){ BAR(); BAR(); }

// ---------------- main fused kernel -----------------------------------------------------
template<bool AS>
__global__ __launch_bounds__(1024) void nge_mfma(
    const int* __restrict__ numbers, const float* __restrict__ adj,
    const float* __restrict__ emb,
    const float* __restrict__ a0, const float* __restrict__ a1,
    const float* __restrict__ a2,
    const float* __restrict__ P1b, const float* __restrict__ P2b,
    const char* __restrict__ wfrag, float* __restrict__ out)
{
  __shared__ float hb[37440];   // 149,760 B: A0 48K | A1 48K | Wh 50.7K | psd 768B
  unsigned short* ab = (unsigned short*)hb;
  float* psd = hb + 37248;

  const int tid  = threadIdx.x;
  const int lane = tid & 63;
  const int w    = tid >> 6;
  const int g    = w >> 3;
  const int wl   = w & 7;
  const int itemg = blockIdx.x*16 + w;

  // gather h0 = emb[numbers], split to hi/lo bf16, group fragment space (KK=4)
  {
    int rows[NN];
    #pragma unroll
    for (int i=0;i<NN;++i) rows[i] = numbers[itemg*NN + i];
    const int half = lane >> 5;
    const int c0   = (lane & 31) << 2;
    const int kk4  = c0 >> 5;
    const int kg2  = (c0 >> 3) & 3;
    const int elem = c0 & 7;
    #pragma unroll
    for (int base=0; base<3; ++base){
      int i = base*2 + half;
      float4 v = *(const float4*)(emb + (size_t)rows[i]*128 + c0);
      ushort4 hv, lv; split4(v, hv, lv);
      int rl = wl*NN + i;
      int mt = rl >> 4;
      int p  = kg2*16 + (rl & 15);
      *(ushort4*)(ab + ACH(g*48 + mt*4 + kk4,      p, kk4) + elem) = hv;
      *(ushort4*)(ab + ACH(g*48 + 12 + mt*4 + kk4, p, kk4) + elem) = lv;
    }
  }
  unsigned long long mz;
  {
    float av = (lane < 36) ? adj[(size_t)itemg*36 + lane] : 1.0f;
    mz = __ballot((lane < 36) && (av == 0.0f));
  }
  BAR();

  f32x4 acc[3][2];
  float nhold[NN][4]; float rshold[NN];

  const char* AS0 = wfrag + OFF_AS0;
  const char* AS1 = wfrag + OFF_AS1;
  const char* AS2 = wfrag + OFF_AS2;

  // ---- staggered GAT layers ----
  if (g == 0) do_gemm<4,AS>(ab, wfrag + OFF_W0, AS0, 0, wl, lane, acc, psd);
  else        idle_step();
  if (g == 0) do_whattn<0,AS>(hb, ab, acc, a0, 0, wl, lane, mz, nhold, rshold, psd);
  else        do_gemm<4,AS>(ab, wfrag + OFF_W0, AS0, 1, wl, lane, acc, psd);

  if (g == 0) do_gemm<8,AS>(ab, wfrag + OFF_W1, AS1, 0, wl, lane, acc, psd);
  else        do_whattn<0,AS>(hb, ab, acc, a0, 1, wl, lane, mz, nhold, rshold, psd);
  if (g == 0) do_whattn<0,AS>(hb, ab, acc, a1, 0, wl, lane, mz, nhold, rshold, psd);
  else        do_gemm<8,AS>(ab, wfrag + OFF_W1, AS1, 1, wl, lane, acc, psd);

  if (g == 0) do_gemm<8,AS>(ab, wfrag + OFF_W2, AS2, 0, wl, lane, acc, psd);
  else        do_whattn<0,AS>(hb, ab, acc, a1, 1, wl, lane, mz, nhold, rshold, psd);
  if (g == 0) do_whattn<1,AS>(hb, ab, acc, a2, 0, wl, lane, mz, nhold, rshold, psd);
  else        do_gemm<8,AS>(ab, wfrag + OFF_W2, AS2, 1, wl, lane, acc, psd);

  if (g == 0){ write_gr(ab, nhold, rshold, wl, lane); BAR(); BAR(); }
  else        do_whattn<2,AS>(hb, ab, acc, a2, 1, wl, lane, mz, nhold, rshold, psd);

  const int arow = lane & 15, kgrp = lane >> 4;

  // ---- P1: x[16][512] = relu(gr[16][1536] @ P1w + P1b); parity accs, depth-3 ----
  {
    f32x4 pa[2][2];
    pa[0][0]=f32x4{0.f,0.f,0.f,0.f}; pa[0][1]=f32x4{0.f,0.f,0.f,0.f};
    pa[1][0]=f32x4{0.f,0.f,0.f,0.f}; pa[1][1]=f32x4{0.f,0.f,0.f,0.f};
    MAKE_AP(ap, ab, (size_t)0);
    const unsigned short* ap48[8];
    #pragma unroll
    for (int t=0;t<8;++t) ap48[t] = ap[t] + 48*512;
    const char* wb0 = wfrag + OFF_P1 + (size_t)(2*w)*48*2048 + (size_t)lane*16;
    const char* wb1 = wb0 + (size_t)48*2048;
    bf16x8 B[4][4];
    GLOADSET(B[0], 0);
    GLOADSET(B[1], 1);
    GLOADSET(B[2], 2);
    #pragma unroll
    for (int kk=0; kk<48; ++kk){
      if (kk+3 < 48) GLOADSET(B[(kk+3)&3], kk+3);
      const int par = kk & 1;
      bf16x8 ah = *(const bf16x8*)(ap[kk&7]   + kk*512);
      bf16x8 al = *(const bf16x8*)(ap48[kk&7] + kk*512);
      __builtin_amdgcn_s_setprio(1);
      pa[par][0] = mfma16(ah, B[kk&3][0], pa[par][0]);
      pa[par][1] = mfma16(ah, B[kk&3][2], pa[par][1]);
      pa[par][0] = mfma16(al, B[kk&3][0], pa[par][0]);
      pa[par][1] = mfma16(al, B[kk&3][2], pa[par][1]);
      pa[par][0] = mfma16(ah, B[kk&3][1], pa[par][0]);
      pa[par][1] = mfma16(ah, B[kk&3][3], pa[par][1]);
      __builtin_amdgcn_s_setprio(0);
    }
    f32x4 pa0, pa1;
    #pragma unroll
    for (int v=0;v<4;++v){ pa0[v] = pa[0][0][v] + pa[1][0][v];
                           pa1[v] = pa[0][1][v] + pa[1][1][v]; }
    BAR();   // gr reads done before x overwrite
    #pragma unroll
    for (int nt=0;nt<2;++nt){
      int col = (2*w+nt)*16 + arow;
      float bv = P1b[col];
      f32x4 pv = nt ? pa1 : pa0;
      int kkx   = w;
      int kgrpx = nt*2 + (arow >> 3);
      int elem  = arow & 7;
      #pragma unroll
      for (int v=0;v<4;++v){
        int item = kgrp*4 + v;
        int p = kgrpx*16 + item;
        float val = fmaxf(pv[v] + bv, 0.f);
        unsigned u = __float_as_uint(val);
        float hf = __uint_as_float(u & 0xFFFF0000u);
        ab[ACH(kkx,      p, kkx) + elem] = (unsigned short)(u >> 16);
        ab[ACH(16 + kkx, p, kkx) + elem] = (unsigned short)(__float_as_uint(val - hf) >> 16);
      }
    }
    BAR();
  }

  // ---- P2: latent[16][128] = x @ P2w + P2b; 16 waves via split-K ----
  {
    float* scr = hb + 8192;
    const int colt  = w & 7;
    const int khalf = w >> 3;
    f32x4 pc = {0.f,0.f,0.f,0.f};
    MAKE_AP(ap, ab, (size_t)0);
    const unsigned short* ap16[8];
    #pragma unroll
    for (int t=0;t<8;++t) ap16[t] = ap[t] + 16*512;
    const char* qb = wfrag + OFF_P2 + (size_t)colt*16*2048 + (size_t)lane*16;
    bf16x8 C[3][2];
    #define QLOADSET(S, kv) do{ \
      (S)[0] = *(const bf16x8*)(qb + (kv)*2048); \
      (S)[1] = *(const bf16x8*)(qb + (kv)*2048 + 1024); } while(0)
    QLOADSET(C[0], khalf*8 + 0);
    QLOADSET(C[1], khalf*8 + 1);
    #pragma unroll
    for (int j=0; j<8; ++j){
      int kk = khalf*8 + j;
      if (j+2 < 8) QLOADSET(C[(j+2)%3], kk+2);
      bf16x8 ah = *(const bf16x8*)(ap[kk&7]   + kk*512);
      bf16x8 al = *(const bf16x8*)(ap16[kk&7] + kk*512);
      __builtin_amdgcn_s_setprio(1);
      pc = mfma16(ah, C[j%3][0], pc);
      pc = mfma16(al, C[j%3][0], pc);
      pc = mfma16(ah, C[j%3][1], pc);
      __builtin_amdgcn_s_setprio(0);
    }
    if (khalf == 1)
      *(f32x4*)(scr + colt*256 + lane*4) = pc;
    BAR();
    if (khalf == 0){
      f32x4 other = *(const f32x4*)(scr + colt*256 + lane*4);
      int col = colt*16 + arow;
      float bv = P2b[col];
      #pragma unroll
      for (int v=0;v<4;++v){
        int itl = kgrp*4 + v;
        size_t ig = (size_t)blockIdx.x*16 + itl;
        float val = pc[v] + other[v] + bv;
        if (col < 64) out[ig*64 + col] = val;
        else          out[(size_t)BTOT*64 + ig*64 + (col - 64)] = val;
      }
    }
  }
}

// ======================= fallback fp32 kernel (ws too small) ===========================
#define EMBD  128
#define HIDD  256
#define PROJD 512
#define LAT2  128
#define TI    16
#define NTHR  1024

template<int K, bool LAST>
__device__ __forceinline__ void gat_layer(
    float* hb, float* st,
    const float* __restrict__ W,
    const float* __restrict__ avec,
    int item, int lane, int tid,
    unsigned long long mz)
{
    const int c0 = lane << 2;
    float wh[NN][4];
    #pragma unroll
    for (int i = 0; i < NN; ++i)
        #pragma unroll
        for (int c = 0; c < 4; ++c) wh[i][c] = 0.f;
    const float* hitem = hb + item * (NN * HIDD);
    for (int k0 = 0; k0 < K; k0 += 32) {
        __syncthreads();
        {
            const int cc = (tid & 63) << 2;
            const int r0 = tid >> 6;
            *(float4*)(st + r0 * HIDD + cc) =
                *(const float4*)(W + (size_t)(k0 + r0) * HIDD + cc);
            *(float4*)(st + (r0 + 16) * HIDD + cc) =
                *(const float4*)(W + (size_t)(k0 + r0 + 16) * HIDD + cc);
        }
        __syncthreads();
        #pragma unroll
        for (int k = 0; k < 32; ++k) {
            const float* hr = hitem + (k0 + k) * NN;
            float2 h01 = *(const float2*)(hr + 0);
            float2 h23 = *(const float2*)(hr + 2);
            float2 h45 = *(const float2*)(hr + 4);
            float av[NN] = {h01.x, h01.y, h23.x, h23.y, h45.x, h45.y};
            float4 bv = *(const float4*)(st + k * HIDD + c0);
            #pragma unroll
            for (int i = 0; i < NN; ++i) {
                wh[i][0] = fmaf(av[i], bv.x, wh[i][0]);
                wh[i][1] = fmaf(av[i], bv.y, wh[i][1]);
                wh[i][2] = fmaf(av[i], bv.z, wh[i][2]);
                wh[i][3] = fmaf(av[i], bv.w, wh[i][3]);
            }
        }
    }
    float4 as4 = *(const float4*)(avec + c0);
    float4 ad4 = *(const float4*)(avec + HIDD + c0);
    float ps[NN], pd[NN];
    #pragma unroll
    for (int i = 0; i < NN; ++i) {
        ps[i] = wh[i][0]*as4.x + wh[i][1]*as4.y + wh[i][2]*as4.z + wh[i][3]*as4.w;
        pd[i] = wh[i][0]*ad4.x + wh[i][1]*ad4.y + wh[i][2]*ad4.z + wh[i][3]*ad4.w;
    }
    for (int off = 32; off > 0; off >>= 1) {
        #pragma unroll
        for (int i = 0; i < NN; ++i) {
            ps[i] += __shfl_xor(ps[i], off);
            pd[i] += __shfl_xor(pd[i], off);
        }
    }
    float rmax[NN];
    #pragma unroll
    for (int i = 0; i < NN; ++i) rmax[i] = -3.4e38f;
    #pragma unroll
    for (int i = 0; i < NN; ++i) {
        #pragma unroll
        for (int j = 0; j < NN; ++j) {
            float e = ps[i] + pd[j];
            e = (e > 0.f) ? e : NEG * e;
            if ((mz >> (i * 6 + j)) & 1ull) e = MASKV;
            rmax[i] = fmaxf(rmax[i], e);
        }
    }
    float rsum[NN] = {0.f, 0.f, 0.f, 0.f, 0.f, 0.f};
    float nh[NN][4];
    #pragma unroll
    for (int i = 0; i < NN; ++i)
        #pragma unroll
        for (int c = 0; c < 4; ++c) nh[i][c] = 0.f;
    #pragma unroll
    for (int j = 0; j < NN; ++j) {
        float s[NN];
        #pragma unroll
        for (int i = 0; i < NN; ++i) {
            float e = ps[i] + pd[j];
            e = (e > 0.f) ? e : NEG * e;
            if ((mz >> (i * 6 + j)) & 1ull) e = MASKV;
            s[i] = expf(e - rmax[i]);
            rsum[i] += s[i];
        }
        #pragma unroll
        for (int i = 0; i < NN; ++i) {
            nh[i][0] = fmaf(s[i], wh[j][0], nh[i][0]);
            nh[i][1] = fmaf(s[i], wh[j][1], nh[i][1]);
            nh[i][2] = fmaf(s[i], wh[j][2], nh[i][2]);
            nh[i][3] = fmaf(s[i], wh[j][3], nh[i][3]);
        }
    }
    float* hout = hb + item * (NN * HIDD);
    #pragma unroll
    for (int i = 0; i < NN; ++i) {
        float rinv = 1.0f / rsum[i];
        if (LAST) {
            float4 v;
            v.x = fmaxf(nh[i][0] * rinv, 0.f);
            v.y = fmaxf(nh[i][1] * rinv, 0.f);
            v.z = fmaxf(nh[i][2] * rinv, 0.f);
            v.w = fmaxf(nh[i][3] * rinv, 0.f);
            *(float4*)(hout + i * HIDD + c0) = v;
        } else {
            #pragma unroll
            for (int c = 0; c < 4; ++c)
                hout[(c0 + c) * NN + i] = fmaxf(nh[i][c] * rinv, 0.f);
        }
    }
}

__global__ __launch_bounds__(NTHR) void nge_fused(
    const int* __restrict__ numbers,
    const float* __restrict__ adj,
    const float* __restrict__ emb,
    const float* __restrict__ W0, const float* __restrict__ a0,
    const float* __restrict__ W1, const float* __restrict__ a1,
    const float* __restrict__ W2, const float* __restrict__ a2,
    const float* __restrict__ P1w, const float* __restrict__ P1b,
    const float* __restrict__ P2w, const float* __restrict__ P2b,
    float* __restrict__ out)
{
    __shared__ float hbuf[TI * NN * HIDD];
    __shared__ float stage[12288];
    const int tid  = threadIdx.x;
    const int lane = tid & 63;
    const int item = tid >> 6;
    const int bidx = blockIdx.x * TI + item;
    {
        int rows[NN];
        #pragma unroll
        for (int i = 0; i < NN; ++i) rows[i] = numbers[bidx * NN + i];
        float* hitem = hbuf + item * (NN * HIDD);
        #pragma unroll
        for (int i = 0; i < NN; ++i) {
            #pragma unroll
            for (int r = 0; r < 2; ++r) {
                int f = lane + (r << 6);
                hitem[f * NN + i] = emb[rows[i] * EMBD + f];
            }
        }
    }
    unsigned long long mz;
    {
        float av = (lane < 36) ? adj[(size_t)bidx * 36 + lane] : 1.0f;
        mz = __ballot((lane < 36) && (av == 0.0f));
    }
    gat_layer<EMBD, false>(hbuf, stage, W0, a0, item, lane, tid, mz);
    gat_layer<HIDD, false>(hbuf, stage, W1, a1, item, lane, tid, mz);
    gat_layer<HIDD, true >(hbuf, stage, W2, a2, item, lane, tid, mz);
    const int ct  = tid & 127;
    const int rt  = tid >> 7;
    const int pc0 = ct << 2;
    float acc[2][4];
    #pragma unroll
    for (int t = 0; t < 2; ++t)
        #pragma unroll
        for (int c = 0; c < 4; ++c) acc[t][c] = 0.f;
    for (int g0 = 0; g0 < NN * HIDD; g0 += 24) {
        __syncthreads();
        #pragma unroll
        for (int s = 0; s < 3; ++s) {
            int r = rt + 8 * s;
            *(float4*)(stage + r * PROJD + pc0) =
                *(const float4*)(P1w + (size_t)(g0 + r) * PROJD + pc0);
        }
        __syncthreads();
        #pragma unroll
        for (int r4 = 0; r4 < 24; r4 += 4) {
            float4 A0 = *(const float4*)(hbuf + rt * (NN * HIDD) + g0 + r4);
            float4 A1 = *(const float4*)(hbuf + (rt + 8) * (NN * HIDD) + g0 + r4);
            const float a0v[4] = {A0.x, A0.y, A0.z, A0.w};
            const float a1v[4] = {A1.x, A1.y, A1.z, A1.w};
            #pragma unroll
            for (int rr = 0; rr < 4; ++rr) {
                float4 bv = *(const float4*)(stage + (r4 + rr) * PROJD + pc0);
                acc[0][0] = fmaf(a0v[rr], bv.x, acc[0][0]);
                acc[0][1] = fmaf(a0v[rr], bv.y, acc[0][1]);
                acc[0][2] = fmaf(a0v[rr], bv.z, acc[0][2]);
                acc[0][3] = fmaf(a0v[rr], bv.w, acc[0][3]);
                acc[1][0] = fmaf(a1v[rr], bv.x, acc[1][0]);
                acc[1][1] = fmaf(a1v[rr], bv.y, acc[1][1]);
                acc[1][2] = fmaf(a1v[rr], bv.z, acc[1][2]);
                acc[1][3] = fmaf(a1v[rr], bv.w, acc[1][3]);
            }
        }
    }
    __syncthreads();
    {
        float4 b1 = *(const float4*)(P1b + pc0);
        #pragma unroll
        for (int t = 0; t < 2; ++t) {
            int it = rt + 8 * t;
            float4 xv;
            xv.x = fmaxf(acc[t][0] + b1.x, 0.f);
            xv.y = fmaxf(acc[t][1] + b1.y, 0.f);
            xv.z = fmaxf(acc[t][2] + b1.z, 0.f);
            xv.w = fmaxf(acc[t][3] + b1.w, 0.f);
            *(float4*)(hbuf + it * PROJD + pc0) = xv;
        }
    }
    const int j0 = lane << 1;
    float acc2x = 0.f, acc2y = 0.f;
    for (int g0 = 0; g0 < PROJD; g0 += 64) {
        __syncthreads();
        {
            int r  = tid >> 5;
            int cc = (tid & 31) << 2;
            *(float4*)(stage + r * LAT2 + cc) =
                *(const float4*)(P2w + (size_t)(g0 + r) * LAT2 + cc);
            *(float4*)(stage + (r + 32) * LAT2 + cc) =
                *(const float4*)(P2w + (size_t)(g0 + r + 32) * LAT2 + cc);
        }
        __syncthreads();
        const float* xit = hbuf + item * PROJD + g0;
        #pragma unroll
        for (int r4 = 0; r4 < 64; r4 += 4) {
            float4 A = *(const float4*)(xit + r4);
            const float av[4] = {A.x, A.y, A.z, A.w};
            #pragma unroll
            for (int rr = 0; rr < 4; ++rr) {
                float2 bv = *(const float2*)(stage + (r4 + rr) * LAT2 + j0);
                acc2x = fmaf(av[rr], bv.x, acc2x);
                acc2y = fmaf(av[rr], bv.y, acc2y);
            }
        }
    }
    {
        float o0 = acc2x + P2b[j0];
        float o1 = acc2y + P2b[j0 + 1];
        size_t base = (size_t)bidx * 64;
        float2 v; v.x = o0; v.y = o1;
        if (j0 < 64) {
            *(float2*)(out + base + j0) = v;
        } else {
            *(float2*)(out + (size_t)BTOT * 64 + base + (j0 - 64)) = v;
        }
    }
}

// ======================= launch =========================================================
extern "C" void kernel_launch(void* const* d_in, const int* in_sizes, int n_in,
                              void* d_out, int out_size, void* d_ws, size_t ws_size,
                              hipStream_t stream) {
    const int*   numbers = (const int*)  d_in[0];
    const float* adj     = (const float*)d_in[1];
    const float* emb     = (const float*)d_in[2];
    const float* W0      = (const float*)d_in[3];
    const float* a0      = (const float*)d_in[4];
    const float* W1      = (const float*)d_in[5];
    const float* a1      = (const float*)d_in[6];
    const float* W2      = (const float*)d_in[7];
    const float* a2      = (const float*)d_in[8];
    const float* P1w     = (const float*)d_in[9];
    const float* P1b     = (const float*)d_in[10];
    const float* P2w     = (const float*)d_in[11];
    const float* P2b     = (const float*)d_in[12];
    float* out = (float*)d_out;

    if (ws_size >= WS_NEED_AS) {
        char* ws = (char*)d_ws;
        fragize<<<2004, 64, 0, stream>>>(W0, W1, W2, P1w, P2w, a0, a1, a2, ws);
        nge_mfma<true><<<BTOT/16, 1024, 0, stream>>>(numbers, adj, emb,
                                                     a0, a1, a2, P1b, P2b, ws, out);
    } else if (ws_size >= WS_NEED) {
        char* ws = (char*)d_ws;
        fragize<<<1984, 64, 0, stream>>>(W0, W1, W2, P1w, P2w, a0, a1, a2, ws);
        nge_mfma<false><<<BTOT/16, 1024, 0, stream>>>(numbers, adj, emb,
                                                      a0, a1, a2, P1b, P2b, ws, out);
    } else {
        nge_fused<<<BTOT/TI, NTHR, 0, stream>>>(numbers, adj, emb,
                                                W0, a0, W1, a1, W2, a2,
                                                P1w, P1b, P2w, P2b, out);
    }
}

// Round 14
// 1055.408 us; speedup vs baseline: 1.2515x; 1.2515x over previous
//
#include <hip/hip_runtime.h>
#include <math.h>

#define BTOT  65536
#define NN    6
#define NEG   0.2f
#define MASKV (-1e9f)

typedef short bf16x8 __attribute__((ext_vector_type(8)));
typedef float f32x4  __attribute__((ext_vector_type(4)));

// ws layout: fragment-linear hi/lo bf16 weights, 1024B per frag, [nt][kk][hi/lo]
#define OFF_W0 0u
#define OFF_W1 131072u
#define OFF_W2 393216u
#define OFF_P1 655360u
#define OFF_P2 3801088u
#define WS_NEED 4063232ull
// appended aS/aD fragments (W@a_src | W@a_dst as B-columns 0,1)
#define OFF_AS0 4063232u
#define OFF_AS1 4071424u
#define OFF_AS2 4087808u
#define WS_NEED_AS 4104192ull

__device__ __forceinline__ f32x4 mfma16(bf16x8 a, bf16x8 b, f32x4 c){
  return __builtin_amdgcn_mfma_f32_16x16x32_bf16(a, b, c, 0, 0, 0);
}

// LDS-only barrier: drain DS ops, hw barrier; vmem register loads stay in flight.
#define BAR() do { \
  asm volatile("s_waitcnt lgkmcnt(0)" ::: "memory"); \
  __builtin_amdgcn_s_barrier(); \
  asm volatile("" ::: "memory"); \
} while (0)

// LDS map: A0 frags [0,48K), A1 [48K,96K), Wh fp32 [96K,145.5K), psd [145.5K,+768B)
#define WH_BASE 24576   // word offset of shared Wh buffer

__device__ __forceinline__ int hwordL(int r, int c){
  return WH_BASE + r*264 + (c ^ ((r&7)<<2));
}
__device__ __forceinline__ int ACH(int frag, int p, int kk){
  return (frag*64 + (p ^ (kk&7) ^ ((p>>4)&3)))*8;
}

// truncation split: x = hi + lo (exact residual)
__device__ __forceinline__ void split4(float4 x, ushort4& h, ushort4& l){
  float xs[4] = {x.x, x.y, x.z, x.w};
  unsigned hu[4], lu[4];
  #pragma unroll
  for (int e=0;e<4;++e){
    unsigned u = __float_as_uint(xs[e]);
    float hf = __uint_as_float(u & 0xFFFF0000u);
    hu[e] = u >> 16;
    lu[e] = __float_as_uint(xs[e] - hf) >> 16;
  }
  h = make_ushort4((unsigned short)hu[0],(unsigned short)hu[1],
                   (unsigned short)hu[2],(unsigned short)hu[3]);
  l = make_ushort4((unsigned short)lu[0],(unsigned short)lu[1],
                   (unsigned short)lu[2],(unsigned short)lu[3]);
}

// ---------------- pre-kernel: fp32 weights -> frag-linear hi/lo bf16 in ws -------------
__global__ __launch_bounds__(64) void fragize(
    const float* __restrict__ W0, const float* __restrict__ W1,
    const float* __restrict__ W2, const float* __restrict__ P1w,
    const float* __restrict__ P2w,
    const float* __restrict__ a0v, const float* __restrict__ a1v,
    const float* __restrict__ a2v, char* __restrict__ ws)
{
  int fid = blockIdx.x;
  int lane = threadIdx.x;
  if (fid >= 1984){
    int idx = fid - 1984;
    const float* W; const float* av; unsigned off; int kk;
    if (idx < 4)       { W = W0; av = a0v; off = OFF_AS0; kk = idx; }
    else if (idx < 12) { W = W1; av = a1v; off = OFF_AS1; kk = idx - 4; }
    else               { W = W2; av = a2v; off = OFF_AS2; kk = idx - 12; }
    int col = lane & 15;
    int kb  = kk*32 + (lane >> 4)*8;
    bf16x8 h, l;
    #pragma unroll
    for (int e=0;e<8;++e){
      float x = 0.f;
      if (col < 2){
        const float* ap = av + col*256;
        const float* wrow = W + (size_t)(kb+e)*256;
        float acc = 0.f;
        for (int o=0;o<256;o+=4){
          float4 wv = *(const float4*)(wrow + o);
          float4 a4 = *(const float4*)(ap + o);
          acc += wv.x*a4.x + wv.y*a4.y + wv.z*a4.z + wv.w*a4.w;
        }
        x = acc;
      }
      unsigned u = __float_as_uint(x);
      float hf = __uint_as_float(u & 0xFFFF0000u);
      h[e] = (short)(u >> 16);
      l[e] = (short)(__float_as_uint(x - hf) >> 16);
    }
    char* dst = ws + off + (size_t)kk*2048 + (size_t)lane*16;
    *(bf16x8*)dst = h;
    *(bf16x8*)(dst + 1024) = l;
    return;
  }
  const float* src; int KK, N; unsigned off; int idx;
  if (fid < 64)        { src = W0;  KK = 4;  N = 256; off = OFF_W0; idx = fid; }
  else if (fid < 192)  { src = W1;  KK = 8;  N = 256; off = OFF_W1; idx = fid - 64; }
  else if (fid < 320)  { src = W2;  KK = 8;  N = 256; off = OFF_W2; idx = fid - 192; }
  else if (fid < 1856) { src = P1w; KK = 48; N = 512; off = OFF_P1; idx = fid - 320; }
  else                 { src = P2w; KK = 16; N = 128; off = OFF_P2; idx = fid - 1856; }
  int nt = idx / KK, kk = idx % KK;
  int n  = nt*16 + (lane & 15);
  int kb = kk*32 + (lane >> 4)*8;
  bf16x8 h, l;
  #pragma unroll
  for (int e=0;e<8;++e){
    float x = src[(size_t)(kb+e)*N + n];
    unsigned u = __float_as_uint(x);
    float hf = __uint_as_float(u & 0xFFFF0000u);
    h[e] = (short)(u >> 16);
    l[e] = (short)(__float_as_uint(x - hf) >> 16);
  }
  char* dst = ws + off + (size_t)idx*2048 + (size_t)lane*16;
  *(bf16x8*)dst = h;
  *(bf16x8*)(dst + 1024) = l;
}

#define GLOADSET(S, kv) do{ \
    (S)[0] = *(const bf16x8*)(wb0 + (kv)*2048); \
    (S)[1] = *(const bf16x8*)(wb0 + (kv)*2048 + 1024); \
    (S)[2] = *(const bf16x8*)(wb1 + (kv)*2048); \
    (S)[3] = *(const bf16x8*)(wb1 + (kv)*2048 + 1024); } while(0)

// ---------------- group GEMM (2 barriers: kk==1 + end) ---------------------------------
// Mid-BAR at kk==1 (1:KK-1 split): the other group's long attn tail overlaps
// the bulk (KK-1 steps) of this GEMM, instead of half of it. No data-ordering
// change (all hazards bracketed by end-of-phase BARs). [R14's single change]
template<int KK, bool AS>
__device__ __forceinline__ void do_gemm(const unsigned short* ab,
    const char* __restrict__ wf, const char* __restrict__ wfS,
    int g, int wl, int lane, f32x4 (&acc)[3][2], float* psd)
{
  const int nq = wl;
  #pragma unroll
  for (int mt=0;mt<3;++mt){
    acc[mt][0] = f32x4{0.f,0.f,0.f,0.f};
    acc[mt][1] = f32x4{0.f,0.f,0.f,0.f};
  }
  const char* wb0 = wf + (size_t)(2*nq)*KK*2048 + (size_t)lane*16;
  const char* wb1 = wb0 + (size_t)KK*2048;
  bf16x8 B[3][4];
  GLOADSET(B[0], 0);
  GLOADSET(B[1], 1);
  const bool doX = AS && (wl >= 5);
  const int mtx = wl - 5;
  const char* wbS = wfS + (size_t)lane*16;
  bf16x8 S[3][2];
  f32x4 accX = {0.f,0.f,0.f,0.f};
  if (doX){
    S[0][0] = *(const bf16x8*)(wbS);
    S[0][1] = *(const bf16x8*)(wbS + 1024);
    S[1][0] = *(const bf16x8*)(wbS + 2048);
    S[1][1] = *(const bf16x8*)(wbS + 2048 + 1024);
  }
  const int abase = g*48;
  #pragma unroll
  for (int kk=0; kk<KK; ++kk){
    if (kk+2 < KK){
      GLOADSET(B[(kk+2)%3], kk+2);
      if (doX){
        S[(kk+2)%3][0] = *(const bf16x8*)(wbS + (kk+2)*2048);
        S[(kk+2)%3][1] = *(const bf16x8*)(wbS + (kk+2)*2048 + 1024);
      }
    }
    if (kk == 1) BAR();
    #pragma unroll
    for (int mt=0; mt<3; ++mt){
      bf16x8 ah = *(const bf16x8*)(ab + ACH(abase + mt*KK + kk,        lane, kk));
      bf16x8 al = *(const bf16x8*)(ab + ACH(abase + 3*KK + mt*KK + kk, lane, kk));
      __builtin_amdgcn_s_setprio(1);
      acc[mt][0] = mfma16(ah, B[kk%3][0], acc[mt][0]);
      acc[mt][1] = mfma16(ah, B[kk%3][2], acc[mt][1]);
      acc[mt][0] = mfma16(al, B[kk%3][0], acc[mt][0]);
      acc[mt][1] = mfma16(al, B[kk%3][2], acc[mt][1]);
      acc[mt][0] = mfma16(ah, B[kk%3][1], acc[mt][0]);
      acc[mt][1] = mfma16(ah, B[kk%3][3], acc[mt][1]);
      if (doX && mt == mtx){
        accX = mfma16(ah, S[kk%3][0], accX);
        accX = mfma16(al, S[kk%3][0], accX);
        accX = mfma16(ah, S[kk%3][1], accX);
      }
      __builtin_amdgcn_s_setprio(0);
    }
  }
  if (doX && (lane & 15) < 2){
    int colx  = lane & 15;
    int rbase = mtx*16 + (lane >> 4)*4;
    #pragma unroll
    for (int v=0;v<4;++v)
      psd[g*96 + (rbase+v)*2 + colx] = accX[v];
  }
  BAR();
}

// gr-write from held attn output
__device__ __forceinline__ void write_gr(unsigned short* ab, const float (*nh)[4],
    const float* rsum, int item_blk, int lane)
{
  const int kkl  = lane >> 3;
  const int kg2  = (lane >> 1) & 3;
  const int elem = (lane & 1) * 4;
  #pragma unroll
  for (int i=0;i<NN;++i){
    float rinv = 1.0f / rsum[i];
    float4 v;
    v.x = fmaxf(nh[i][0]*rinv, 0.f);
    v.y = fmaxf(nh[i][1]*rinv, 0.f);
    v.z = fmaxf(nh[i][2]*rinv, 0.f);
    v.w = fmaxf(nh[i][3]*rinv, 0.f);
    ushort4 hv, lv; split4(v, hv, lv);
    int kkg = i*8 + kkl;
    int p   = kg2*16 + item_blk;
    *(ushort4*)(ab + ACH(kkg,      p, kkg) + elem) = hv;
    *(ushort4*)(ab + ACH(48 + kkg, p, kkg) + elem) = lv;
  }
}

// ---------------- Wh-write + attention (2 barriers); scalar math -----------------------
// MODE 0: write h' to own A-frags. MODE 1: hold. MODE 2: write gr.
template<int MODE, bool AS>
__device__ __forceinline__ void do_whattn(float* hb, unsigned short* ab,
    const f32x4 (&acc)[3][2], const float* __restrict__ avec,
    int g, int wl, int lane, unsigned long long mz,
    float (*nhold)[4], float* rshold, const float* psd)
{
  const int arow = lane & 15, kgrp = lane >> 4;
  #pragma unroll
  for (int mt=0;mt<3;++mt)
    #pragma unroll
    for (int nt=0;nt<2;++nt)
      #pragma unroll
      for (int v=0;v<4;++v)
        hb[hwordL(mt*16 + kgrp*4 + v, (wl*2+nt)*16 + arow)] = acc[mt][nt][v];
  BAR();

  const int c0 = lane << 2;
  float wh[NN][4];
  #pragma unroll
  for (int i=0;i<NN;++i){
    float4 t = *(const float4*)(hb + hwordL(wl*NN+i, c0));
    wh[i][0]=t.x; wh[i][1]=t.y; wh[i][2]=t.z; wh[i][3]=t.w;
  }
  float ps[NN], pd[NN];
  if (AS){
    #pragma unroll
    for (int i=0;i<NN;++i){
      float2 t = *(const float2*)(psd + g*96 + (wl*NN+i)*2);
      ps[i] = t.x; pd[i] = t.y;
    }
  } else {
    float4 as4 = *(const float4*)(avec + c0);
    float4 ad4 = *(const float4*)(avec + 256 + c0);
    #pragma unroll
    for (int i=0;i<NN;++i){
      ps[i] = wh[i][0]*as4.x + wh[i][1]*as4.y + wh[i][2]*as4.z + wh[i][3]*as4.w;
      pd[i] = wh[i][0]*ad4.x + wh[i][1]*ad4.y + wh[i][2]*ad4.z + wh[i][3]*ad4.w;
    }
    for (int off=32; off>0; off>>=1){
      #pragma unroll
      for (int i=0;i<NN;++i){ ps[i]+=__shfl_xor(ps[i],off); pd[i]+=__shfl_xor(pd[i],off); }
    }
  }
  // rmax via monotonicity of leaky: max_j leaky(ps+pd_j) = leaky(ps + max_j pd_j)
  float rmax[NN];
  #pragma unroll
  for (int i=0;i<NN;++i){
    float mp = -3.4e38f;
    #pragma unroll
    for (int j=0;j<NN;++j){
      float pj = ((mz >> (i*6+j)) & 1ull) ? -3.4e38f : pd[j];
      mp = fmaxf(mp, pj);
    }
    float t  = ps[i] + mp;
    float lk = fmaxf(t, NEG*t);
    rmax[i] = fmaxf(lk, MASKV);
  }
  float rsum[NN] = {0.f,0.f,0.f,0.f,0.f,0.f};
  float nh[NN][4];
  #pragma unroll
  for (int i=0;i<NN;++i){ nh[i][0]=0.f; nh[i][1]=0.f; nh[i][2]=0.f; nh[i][3]=0.f; }
  #pragma unroll
  for (int j=0;j<NN;++j){
    float s[NN];
    #pragma unroll
    for (int i=0;i<NN;++i){
      float t = ps[i] + pd[j];
      float e = fmaxf(t, NEG*t);
      e = ((mz >> (i*6+j)) & 1ull) ? MASKV : e;
      s[i] = __expf(e - rmax[i]);
      rsum[i] += s[i];
    }
    #pragma unroll
    for (int i=0;i<NN;++i){
      nh[i][0] = fmaf(s[i], wh[j][0], nh[i][0]);
      nh[i][1] = fmaf(s[i], wh[j][1], nh[i][1]);
      nh[i][2] = fmaf(s[i], wh[j][2], nh[i][2]);
      nh[i][3] = fmaf(s[i], wh[j][3], nh[i][3]);
    }
  }

  if (MODE == 0){
    const int kkl  = lane >> 3;
    const int kg2  = (lane >> 1) & 3;
    const int elem = (lane & 1) * 4;
    #pragma unroll
    for (int i=0;i<NN;++i){
      float rinv = 1.0f / rsum[i];
      float4 v;
      v.x = fmaxf(nh[i][0]*rinv, 0.f);
      v.y = fmaxf(nh[i][1]*rinv, 0.f);
      v.z = fmaxf(nh[i][2]*rinv, 0.f);
      v.w = fmaxf(nh[i][3]*rinv, 0.f);
      ushort4 hv, lv; split4(v, hv, lv);
      int rl = wl*NN + i;
      int mt = rl >> 4;
      int p  = kg2*16 + (rl & 15);
      *(ushort4*)(ab + ACH(g*48 + mt*8 + kkl,      p, kkl) + elem) = hv;
      *(ushort4*)(ab + ACH(g*48 + 24 + mt*8 + kkl, p, kkl) + elem) = lv;
    }
  } else if (MODE == 1){
    #pragma unroll
    for (int i=0;i<NN;++i){
      nhold[i][0]=nh[i][0]; nhold[i][1]=nh[i][1];
      nhold[i][2]=nh[i][2]; nhold[i][3]=nh[i][3];
      rshold[i]=rsum[i];
    }
  } else {
    write_gr(ab, nh, rsum, g*8 + wl, lane);
  }
  BAR();
}

__device__ __forceinline__ void idle_step(){ BAR(); BAR(); }

// ---------------- main fused kernel -----------------------------------------------------
template<bool AS>
__global__ __launch_bounds__(1024, 4) void nge_mfma(
    const int* __restrict__ numbers, const float* __restrict__ adj,
    const float* __restrict__ emb,
    const float* __restrict__ a0, const float* __restrict__ a1,
    const float* __restrict__ a2,
    const float* __restrict__ P1b, const float* __restrict__ P2b,
    const char* __restrict__ wfrag, float* __restrict__ out)
{
  __shared__ float hb[37440];   // 149,760 B: A0 48K | A1 48K | Wh 50.7K | psd 768B
  unsigned short* ab = (unsigned short*)hb;
  float* psd = hb + 37248;

  const int tid  = threadIdx.x;
  const int lane = tid & 63;
  const int w    = tid >> 6;
  const int g    = w >> 3;
  const int wl   = w & 7;
  const int itemg = blockIdx.x*16 + w;

  // gather h0 = emb[numbers], split to hi/lo bf16, group fragment space (KK=4)
  {
    int rows[NN];
    #pragma unroll
    for (int i=0;i<NN;++i) rows[i] = numbers[itemg*NN + i];
    const int half = lane >> 5;
    const int c0   = (lane & 31) << 2;
    const int kk4  = c0 >> 5;
    const int kg2  = (c0 >> 3) & 3;
    const int elem = c0 & 7;
    #pragma unroll
    for (int base=0; base<3; ++base){
      int i = base*2 + half;
      float4 v = *(const float4*)(emb + (size_t)rows[i]*128 + c0);
      ushort4 hv, lv; split4(v, hv, lv);
      int rl = wl*NN + i;
      int mt = rl >> 4;
      int p  = kg2*16 + (rl & 15);
      *(ushort4*)(ab + ACH(g*48 + mt*4 + kk4,      p, kk4) + elem) = hv;
      *(ushort4*)(ab + ACH(g*48 + 12 + mt*4 + kk4, p, kk4) + elem) = lv;
    }
  }
  unsigned long long mz;
  {
    float av = (lane < 36) ? adj[(size_t)itemg*36 + lane] : 1.0f;
    mz = __ballot((lane < 36) && (av == 0.0f));
  }
  BAR();

  f32x4 acc[3][2];
  float nhold[NN][4]; float rshold[NN];

  const char* AS0 = wfrag + OFF_AS0;
  const char* AS1 = wfrag + OFF_AS1;
  const char* AS2 = wfrag + OFF_AS2;

  // ---- staggered GAT layers ----
  if (g == 0) do_gemm<4,AS>(ab, wfrag + OFF_W0, AS0, 0, wl, lane, acc, psd);
  else        idle_step();
  if (g == 0) do_whattn<0,AS>(hb, ab, acc, a0, 0, wl, lane, mz, nhold, rshold, psd);
  else        do_gemm<4,AS>(ab, wfrag + OFF_W0, AS0, 1, wl, lane, acc, psd);

  if (g == 0) do_gemm<8,AS>(ab, wfrag + OFF_W1, AS1, 0, wl, lane, acc, psd);
  else        do_whattn<0,AS>(hb, ab, acc, a0, 1, wl, lane, mz, nhold, rshold, psd);
  if (g == 0) do_whattn<0,AS>(hb, ab, acc, a1, 0, wl, lane, mz, nhold, rshold, psd);
  else        do_gemm<8,AS>(ab, wfrag + OFF_W1, AS1, 1, wl, lane, acc, psd);

  if (g == 0) do_gemm<8,AS>(ab, wfrag + OFF_W2, AS2, 0, wl, lane, acc, psd);
  else        do_whattn<0,AS>(hb, ab, acc, a1, 1, wl, lane, mz, nhold, rshold, psd);
  if (g == 0) do_whattn<1,AS>(hb, ab, acc, a2, 0, wl, lane, mz, nhold, rshold, psd);
  else        do_gemm<8,AS>(ab, wfrag + OFF_W2, AS2, 1, wl, lane, acc, psd);

  if (g == 0){ write_gr(ab, nhold, rshold, wl, lane); BAR(); BAR(); }
  else        do_whattn<2,AS>(hb, ab, acc, a2, 1, wl, lane, mz, nhold, rshold, psd);

  const int arow = lane & 15, kgrp = lane >> 4;

  // ---- P1: x[16][512] = relu(gr[16][1536] @ P1w + P1b); parity accs, depth-3 ----
  {
    f32x4 pa[2][2];
    pa[0][0]=f32x4{0.f,0.f,0.f,0.f}; pa[0][1]=f32x4{0.f,0.f,0.f,0.f};
    pa[1][0]=f32x4{0.f,0.f,0.f,0.f}; pa[1][1]=f32x4{0.f,0.f,0.f,0.f};
    const char* wb0 = wfrag + OFF_P1 + (size_t)(2*w)*48*2048 + (size_t)lane*16;
    const char* wb1 = wb0 + (size_t)48*2048;
    bf16x8 B[4][4];
    GLOADSET(B[0], 0);
    GLOADSET(B[1], 1);
    GLOADSET(B[2], 2);
    #pragma unroll
    for (int kk=0; kk<48; ++kk){
      if (kk+3 < 48) GLOADSET(B[(kk+3)%4], kk+3);
      const int par = kk & 1;
      bf16x8 ah = *(const bf16x8*)(ab + ACH(kk,      lane, kk));
      bf16x8 al = *(const bf16x8*)(ab + ACH(48 + kk, lane, kk));
      __builtin_amdgcn_s_setprio(1);
      pa[par][0] = mfma16(ah, B[kk%4][0], pa[par][0]);
      pa[par][1] = mfma16(ah, B[kk%4][2], pa[par][1]);
      pa[par][0] = mfma16(al, B[kk%4][0], pa[par][0]);
      pa[par][1] = mfma16(al, B[kk%4][2], pa[par][1]);
      pa[par][0] = mfma16(ah, B[kk%4][1], pa[par][0]);
      pa[par][1] = mfma16(ah, B[kk%4][3], pa[par][1]);
      __builtin_amdgcn_s_setprio(0);
    }
    f32x4 pa0, pa1;
    #pragma unroll
    for (int v=0;v<4;++v){ pa0[v] = pa[0][0][v] + pa[1][0][v];
                           pa1[v] = pa[0][1][v] + pa[1][1][v]; }
    BAR();   // gr reads done before x overwrite
    #pragma unroll
    for (int nt=0;nt<2;++nt){
      int col = (2*w+nt)*16 + arow;
      float bv = P1b[col];
      f32x4 pv = nt ? pa1 : pa0;
      int kkx   = w;
      int kgrpx = nt*2 + (arow >> 3);
      int elem  = arow & 7;
      #pragma unroll
      for (int v=0;v<4;++v){
        int item = kgrp*4 + v;
        int p = kgrpx*16 + item;
        float val = fmaxf(pv[v] + bv, 0.f);
        unsigned u = __float_as_uint(val);
        float hf = __uint_as_float(u & 0xFFFF0000u);
        ab[ACH(kkx,      p, kkx) + elem] = (unsigned short)(u >> 16);
        ab[ACH(16 + kkx, p, kkx) + elem] = (unsigned short)(__float_as_uint(val - hf) >> 16);
      }
    }
    BAR();
  }

  // ---- P2: latent[16][128] = x @ P2w + P2b; 16 waves via split-K ----
  {
    float* scr = hb + 8192;
    const int colt  = w & 7;
    const int khalf = w >> 3;
    f32x4 pc = {0.f,0.f,0.f,0.f};
    const char* qb = wfrag + OFF_P2 + (size_t)colt*16*2048 + (size_t)lane*16;
    bf16x8 C[3][2];
    #define QLOADSET(S, kv) do{ \
      (S)[0] = *(const bf16x8*)(qb + (kv)*2048); \
      (S)[1] = *(const bf16x8*)(qb + (kv)*2048 + 1024); } while(0)
    QLOADSET(C[0], khalf*8 + 0);
    QLOADSET(C[1], khalf*8 + 1);
    #pragma unroll
    for (int j=0; j<8; ++j){
      int kk = khalf*8 + j;
      if (j+2 < 8) QLOADSET(C[(j+2)%3], kk+2);
      bf16x8 ah = *(const bf16x8*)(ab + ACH(kk,      lane, kk));
      bf16x8 al = *(const bf16x8*)(ab + ACH(16 + kk, lane, kk));
      __builtin_amdgcn_s_setprio(1);
      pc = mfma16(ah, C[j%3][0], pc);
      pc = mfma16(al, C[j%3][0], pc);
      pc = mfma16(ah, C[j%3][1], pc);
      __builtin_amdgcn_s_setprio(0);
    }
    if (khalf == 1)
      *(f32x4*)(scr + colt*256 + lane*4) = pc;
    BAR();
    if (khalf == 0){
      f32x4 other = *(const f32x4*)(scr + colt*256 + lane*4);
      int col = colt*16 + arow;
      float bv = P2b[col];
      #pragma unroll
      for (int v=0;v<4;++v){
        int itl = kgrp*4 + v;
        size_t ig = (size_t)blockIdx.x*16 + itl;
        float val = pc[v] + other[v] + bv;
        if (col < 64) out[ig*64 + col] = val;
        else          out[(size_t)BTOT*64 + ig*64 + (col - 64)] = val;
      }
    }
  }
}

// ======================= fallback fp32 kernel (ws too small) ===========================
#define EMBD  128
#define HIDD  256
#define PROJD 512
#define LAT2  128
#define TI    16
#define NTHR  1024

template<int K, bool LAST>
__device__ __forceinline__ void gat_layer(
    float* hb, float* st,
    const float* __restrict__ W,
    const float* __restrict__ avec,
    int item, int lane, int tid,
    unsigned long long mz)
{
    const int c0 = lane << 2;
    float wh[NN][4];
    #pragma unroll
    for (int i = 0; i < NN; ++i)
        #pragma unroll
        for (int c = 0; c < 4; ++c) wh[i][c] = 0.f;
    const float* hitem = hb + item * (NN * HIDD);
    for (int k0 = 0; k0 < K; k0 += 32) {
        __syncthreads();
        {
            const int cc = (tid & 63) << 2;
            const int r0 = tid >> 6;
            *(float4*)(st + r0 * HIDD + cc) =
                *(const float4*)(W + (size_t)(k0 + r0) * HIDD + cc);
            *(float4*)(st + (r0 + 16) * HIDD + cc) =
                *(const float4*)(W + (size_t)(k0 + r0 + 16) * HIDD + cc);
        }
        __syncthreads();
        #pragma unroll
        for (int k = 0; k < 32; ++k) {
            const float* hr = hitem + (k0 + k) * NN;
            float2 h01 = *(const float2*)(hr + 0);
            float2 h23 = *(const float2*)(hr + 2);
            float2 h45 = *(const float2*)(hr + 4);
            float av[NN] = {h01.x, h01.y, h23.x, h23.y, h45.x, h45.y};
            float4 bv = *(const float4*)(st + k * HIDD + c0);
            #pragma unroll
            for (int i = 0; i < NN; ++i) {
                wh[i][0] = fmaf(av[i], bv.x, wh[i][0]);
                wh[i][1] = fmaf(av[i], bv.y, wh[i][1]);
                wh[i][2] = fmaf(av[i], bv.z, wh[i][2]);
                wh[i][3] = fmaf(av[i], bv.w, wh[i][3]);
            }
        }
    }
    float4 as4 = *(const float4*)(avec + c0);
    float4 ad4 = *(const float4*)(avec + HIDD + c0);
    float ps[NN], pd[NN];
    #pragma unroll
    for (int i = 0; i < NN; ++i) {
        ps[i] = wh[i][0]*as4.x + wh[i][1]*as4.y + wh[i][2]*as4.z + wh[i][3]*as4.w;
        pd[i] = wh[i][0]*ad4.x + wh[i][1]*ad4.y + wh[i][2]*ad4.z + wh[i][3]*ad4.w;
    }
    for (int off = 32; off > 0; off >>= 1) {
        #pragma unroll
        for (int i = 0; i < NN; ++i) {
            ps[i] += __shfl_xor(ps[i], off);
            pd[i] += __shfl_xor(pd[i], off);
        }
    }
    float rmax[NN];
    #pragma unroll
    for (int i = 0; i < NN; ++i) rmax[i] = -3.4e38f;
    #pragma unroll
    for (int i = 0; i < NN; ++i) {
        #pragma unroll
        for (int j = 0; j < NN; ++j) {
            float e = ps[i] + pd[j];
            e = (e > 0.f) ? e : NEG * e;
            if ((mz >> (i * 6 + j)) & 1ull) e = MASKV;
            rmax[i] = fmaxf(rmax[i], e);
        }
    }
    float rsum[NN] = {0.f, 0.f, 0.f, 0.f, 0.f, 0.f};
    float nh[NN][4];
    #pragma unroll
    for (int i = 0; i < NN; ++i)
        #pragma unroll
        for (int c = 0; c < 4; ++c) nh[i][c] = 0.f;
    #pragma unroll
    for (int j = 0; j < NN; ++j) {
        float s[NN];
        #pragma unroll
        for (int i = 0; i < NN; ++i) {
            float e = ps[i] + pd[j];
            e = (e > 0.f) ? e : NEG * e;
            if ((mz >> (i * 6 + j)) & 1ull) e = MASKV;
            s[i] = expf(e - rmax[i]);
            rsum[i] += s[i];
        }
        #pragma unroll
        for (int i = 0; i < NN; ++i) {
            nh[i][0] = fmaf(s[i], wh[j][0], nh[i][0]);
            nh[i][1] = fmaf(s[i], wh[j][1], nh[i][1]);
            nh[i][2] = fmaf(s[i], wh[j][2], nh[i][2]);
            nh[i][3] = fmaf(s[i], wh[j][3], nh[i][3]);
        }
    }
    float* hout = hb + item * (NN * HIDD);
    #pragma unroll
    for (int i = 0; i < NN; ++i) {
        float rinv = 1.0f / rsum[i];
        if (LAST) {
            float4 v;
            v.x = fmaxf(nh[i][0] * rinv, 0.f);
            v.y = fmaxf(nh[i][1] * rinv, 0.f);
            v.z = fmaxf(nh[i][2] * rinv, 0.f);
            v.w = fmaxf(nh[i][3] * rinv, 0.f);
            *(float4*)(hout + i * HIDD + c0) = v;
        } else {
            #pragma unroll
            for (int c = 0; c < 4; ++c)
                hout[(c0 + c) * NN + i] = fmaxf(nh[i][c] * rinv, 0.f);
        }
    }
}

__global__ __launch_bounds__(NTHR) void nge_fused(
    const int* __restrict__ numbers,
    const float* __restrict__ adj,
    const float* __restrict__ emb,
    const float* __restrict__ W0, const float* __restrict__ a0,
    const float* __restrict__ W1, const float* __restrict__ a1,
    const float* __restrict__ W2, const float* __restrict__ a2,
    const float* __restrict__ P1w, const float* __restrict__ P1b,
    const float* __restrict__ P2w, const float* __restrict__ P2b,
    float* __restrict__ out)
{
    __shared__ float hbuf[TI * NN * HIDD];
    __shared__ float stage[12288];
    const int tid  = threadIdx.x;
    const int lane = tid & 63;
    const int item = tid >> 6;
    const int bidx = blockIdx.x * TI + item;
    {
        int rows[NN];
        #pragma unroll
        for (int i = 0; i < NN; ++i) rows[i] = numbers[bidx * NN + i];
        float* hitem = hbuf + item * (NN * HIDD);
        #pragma unroll
        for (int i = 0; i < NN; ++i) {
            #pragma unroll
            for (int r = 0; r < 2; ++r) {
                int f = lane + (r << 6);
                hitem[f * NN + i] = emb[rows[i] * EMBD + f];
            }
        }
    }
    unsigned long long mz;
    {
        float av = (lane < 36) ? adj[(size_t)bidx * 36 + lane] : 1.0f;
        mz = __ballot((lane < 36) && (av == 0.0f));
    }
    gat_layer<EMBD, false>(hbuf, stage, W0, a0, item, lane, tid, mz);
    gat_layer<HIDD, false>(hbuf, stage, W1, a1, item, lane, tid, mz);
    gat_layer<HIDD, true >(hbuf, stage, W2, a2, item, lane, tid, mz);
    const int ct  = tid & 127;
    const int rt  = tid >> 7;
    const int pc0 = ct << 2;
    float acc[2][4];
    #pragma unroll
    for (int t = 0; t < 2; ++t)
        #pragma unroll
        for (int c = 0; c < 4; ++c) acc[t][c] = 0.f;
    for (int g0 = 0; g0 < NN * HIDD; g0 += 24) {
        __syncthreads();
        #pragma unroll
        for (int s = 0; s < 3; ++s) {
            int r = rt + 8 * s;
            *(float4*)(stage + r * PROJD + pc0) =
                *(const float4*)(P1w + (size_t)(g0 + r) * PROJD + pc0);
        }
        __syncthreads();
        #pragma unroll
        for (int r4 = 0; r4 < 24; r4 += 4) {
            float4 A0 = *(const float4*)(hbuf + rt * (NN * HIDD) + g0 + r4);
            float4 A1 = *(const float4*)(hbuf + (rt + 8) * (NN * HIDD) + g0 + r4);
            const float a0v[4] = {A0.x, A0.y, A0.z, A0.w};
            const float a1v[4] = {A1.x, A1.y, A1.z, A1.w};
            #pragma unroll
            for (int rr = 0; rr < 4; ++rr) {
                float4 bv = *(const float4*)(stage + (r4 + rr) * PROJD + pc0);
                acc[0][0] = fmaf(a0v[rr], bv.x, acc[0][0]);
                acc[0][1] = fmaf(a0v[rr], bv.y, acc[0][1]);
                acc[0][2] = fmaf(a0v[rr], bv.z, acc[0][2]);
                acc[0][3] = fmaf(a0v[rr], bv.w, acc[0][3]);
                acc[1][0] = fmaf(a1v[rr], bv.x, acc[1][0]);
                acc[1][1] = fmaf(a1v[rr], bv.y, acc[1][1]);
                acc[1][2] = fmaf(a1v[rr], bv.z, acc[1][2]);
                acc[1][3] = fmaf(a1v[rr], bv.w, acc[1][3]);
            }
        }
    }
    __syncthreads();
    {
        float4 b1 = *(const float4*)(P1b + pc0);
        #pragma unroll
        for (int t = 0; t < 2; ++t) {
            int it = rt + 8 * t;
            float4 xv;
            xv.x = fmaxf(acc[t][0] + b1.x, 0.f);
            xv.y = fmaxf(acc[t][1] + b1.y, 0.f);
            xv.z = fmaxf(acc[t][2] + b1.z, 0.f);
            xv.w = fmaxf(acc[t][3] + b1.w, 0.f);
            *(float4*)(hbuf + it * PROJD + pc0) = xv;
        }
    }
    const int j0 = lane << 1;
    float acc2x = 0.f, acc2y = 0.f;
    for (int g0 = 0; g0 < PROJD; g0 += 64) {
        __syncthreads();
        {
            int r  = tid >> 5;
            int cc = (tid & 31) << 2;
            *(float4*)(stage + r * LAT2 + cc) =
                *(const float4*)(P2w + (size_t)(g0 + r) * LAT2 + cc);
            *(float4*)(stage + (r + 32) * LAT2 + cc) =
                *(const float4*)(P2w + (size_t)(g0 + r + 32) * LAT2 + cc);
        }
        __syncthreads();
        const float* xit = hbuf + item * PROJD + g0;
        #pragma unroll
        for (int r4 = 0; r4 < 64; r4 += 4) {
            float4 A = *(const float4*)(xit + r4);
            const float av[4] = {A.x, A.y, A.z, A.w};
            #pragma unroll
            for (int rr = 0; rr < 4; ++rr) {
                float2 bv = *(const float2*)(stage + (r4 + rr) * LAT2 + j0);
                acc2x = fmaf(av[rr], bv.x, acc2x);
                acc2y = fmaf(av[rr], bv.y, acc2y);
            }
        }
    }
    {
        float o0 = acc2x + P2b[j0];
        float o1 = acc2y + P2b[j0 + 1];
        size_t base = (size_t)bidx * 64;
        float2 v; v.x = o0; v.y = o1;
        if (j0 < 64) {
            *(float2*)(out + base + j0) = v;
        } else {
            *(float2*)(out + (size_t)BTOT * 64 + base + (j0 - 64)) = v;
        }
    }
}

// ======================= launch =========================================================
extern "C" void kernel_launch(void* const* d_in, const int* in_sizes, int n_in,
                              void* d_out, int out_size, void* d_ws, size_t ws_size,
                              hipStream_t stream) {
    const int*   numbers = (const int*)  d_in[0];
    const float* adj     = (const float*)d_in[1];
    const float* emb     = (const float*)d_in[2];
    const float* W0      = (const float*)d_in[3];
    const float* a0      = (const float*)d_in[4];
    const float* W1      = (const float*)d_in[5];
    const float* a1      = (const float*)d_in[6];
    const float* W2      = (const float*)d_in[7];
    const float* a2      = (const float*)d_in[8];
    const float* P1w     = (const float*)d_in[9];
    const float* P1b     = (const float*)d_in[10];
    const float* P2w     = (const float*)d_in[11];
    const float* P2b     = (const float*)d_in[12];
    float* out = (float*)d_out;

    if (ws_size >= WS_NEED_AS) {
        char* ws = (char*)d_ws;
        fragize<<<2004, 64, 0, stream>>>(W0, W1, W2, P1w, P2w, a0, a1, a2, ws);
        nge_mfma<true><<<BTOT/16, 1024, 0, stream>>>(numbers, adj, emb,
                                                     a0, a1, a2, P1b, P2b, ws, out);
    } else if (ws_size >= WS_NEED) {
        char* ws = (char*)d_ws;
        fragize<<<1984, 64, 0, stream>>>(W0, W1, W2, P1w, P2w, a0, a1, a2, ws);
        nge_mfma<false><<<BTOT/16, 1024, 0, stream>>>(numbers, adj, emb,
                                                      a0, a1, a2, P1b, P2b, ws, out);
    } else {
        nge_fused<<<BTOT/TI, NTHR, 0, stream>>>(numbers, adj, emb,
                                                W0, a0, W1, a1, W2, a2,
                                                P1w, P1b, P2w, P2b, out);
    }
}